// Round 2
// baseline (127.675 us; speedup 1.0000x reference)
//
#include <hip/hip_runtime.h>

// MS_SSA_Conv: spiking self-attention, T=4, C=512, N=196 (14x14), fp32.
// All matmul inputs are spikes {0,1} at low density -> sparse masked
// column-sums of W^T instead of dense GEMM.
//
// v2 restructure (latency-bound fix; prior version was 0.77 waves/SIMD with a
// serial dependent load chain):
//  k0: transpose weights into Wt[c][o] with an extra ZEROED row c=512 (pad
//      target), zero kvsum, and (extra 196 blocks) run shortcut-LIF per token,
//      building DETERMINISTIC ascending-c active-channel lists in ws, padded
//      to a multiple of 8 with c=512.
//  ka: grid 392 = (n, half): 1 output channel per thread. Inner loop reads 8
//      list entries with one uniform uint4 load, readfirstlane -> SGPR row
//      base, 24 independent coalesced dword loads per group (ILP-8).
//      BN+LIF -> sq bitmask store, atomicAdd(sk&sv) into kvsum.
//  kb: grid 392: talking-heads LIF on kvsum, AND with sq bits, deterministic
//      compact in LDS, ILP-8 sparse accumulate of proj, bias+BN epilogue into
//      coalesced outT[t][n][c].
//  k2: tiled transpose outT -> out[t][c][n] + identity x (both sides coalesced).

#define TT 4
#define CC 512
#define NN 196
#define BEPS 1e-5f

// ws layout in floats. Weight mats have 513 rows (row 512 zeroed = pad row).
#define WQT_OFF 0
#define WKT_OFF (513 * 512)
#define WVT_OFF (2 * 513 * 512)
#define WPT_OFF (3 * 513 * 512)
#define KV_OFF  (4 * 513 * 512)          // T*C = 2048 floats
#define SQ_OFF  (KV_OFF + 2048)          // T*N*16 u32 words = 12544
#define ACT_OFF (SQ_OFF + 12544)         // T*N*512 ushorts = 200704 floats
#define CNT_OFF (ACT_OFF + 200704)       // T*N ints = 784
#define OT_OFF  (CNT_OFF + 784)          // T*N*C floats = 401408
// total ~1.67M floats = 6.7 MB of ws

__global__ __launch_bounds__(256) void k0_prep(
    const float* __restrict__ qw, const float* __restrict__ kw,
    const float* __restrict__ vw, const float* __restrict__ pw,
    const float* __restrict__ x, float* __restrict__ ws)
{
    const int b   = blockIdx.x;
    const int tid = threadIdx.x;

    if (b < 256) {
        // ---- weight transpose: 4 matrices x 64 tiles of 64x64 ----
        __shared__ float tile[64][65];
        const int mat = b >> 6;
        const int t6  = b & 63;
        const int to  = (t6 >> 3) * 64;
        const int tc  = (t6 & 7) * 64;
        const float* W = (mat == 0) ? qw : (mat == 1) ? kw : (mat == 2) ? vw : pw;
        float* Wt = ws + (size_t)mat * (513 * 512);
        const int lr = tid >> 6;
        const int lc = tid & 63;
#pragma unroll
        for (int i = 0; i < 16; ++i) {
            int r = i * 4 + lr;
            tile[r][lc] = W[(size_t)(to + r) * 512 + (tc + lc)];
        }
        __syncthreads();
#pragma unroll
        for (int i = 0; i < 16; ++i) {
            int r = i * 4 + lr;
            Wt[(size_t)(tc + r) * 512 + (to + lc)] = tile[lc][r];
        }
        if (t6 == 0) {  // zero the pad row c=512
            for (int i = tid; i < 512; i += 256) Wt[(size_t)512 * 512 + i] = 0.0f;
        }
        if (b == 0) {
            for (int i = tid; i < TT * CC; i += 256) ws[KV_OFF + i] = 0.0f;
        }
        return;
    }

    // ---- shortcut LIF + deterministic active-list build, one block per n ----
    const int n    = b - 256;
    const int lane = tid & 63;
    const int wave = tid >> 6;
    __shared__ unsigned long long msk[TT][8];

    int xf0 = 0, xf1 = 0;
    {
        float v0 = 0.0f, v1 = 0.0f;
#pragma unroll
        for (int t = 0; t < TT; ++t) {
            float a0 = x[(size_t)(t * CC + tid) * NN + n];
            float a1 = x[(size_t)(t * CC + tid + 256) * NN + n];
            v0 = v0 + (a0 - v0) * 0.5f;
            v1 = v1 + (a1 - v1) * 0.5f;
            if (v0 >= 1.0f) { xf0 |= (1 << t); v0 = 0.0f; }
            if (v1 >= 1.0f) { xf1 |= (1 << t); v1 = 0.0f; }
        }
    }
#pragma unroll
    for (int t = 0; t < TT; ++t) {
        unsigned long long m0 = __ballot((xf0 >> t) & 1);
        unsigned long long m1 = __ballot((xf1 >> t) & 1);
        if (lane == 0) { msk[t][wave] = m0; msk[t][4 + wave] = m1; }
    }
    __syncthreads();

    unsigned short* actg = (unsigned short*)(ws + ACT_OFF);
    int* cntg = (int*)(ws + CNT_OFF);
    const unsigned long long ltm = (1ull << lane) - 1ull;
#pragma unroll
    for (int t = 0; t < TT; ++t) {
        unsigned short* row = actg + ((size_t)t * NN + n) * 512;
        if ((xf0 >> t) & 1) {
            int base = 0;
            for (int s2 = 0; s2 < wave; ++s2) base += __popcll(msk[t][s2]);
            base += __popcll(msk[t][wave] & ltm);
            row[base] = (unsigned short)tid;
        }
        if ((xf1 >> t) & 1) {
            int base = 0;
            for (int s2 = 0; s2 < 4 + wave; ++s2) base += __popcll(msk[t][s2]);
            base += __popcll(msk[t][4 + wave] & ltm);
            row[base] = (unsigned short)(tid + 256);
        }
    }
    if (tid < TT) {
        int tot = 0;
#pragma unroll
        for (int s2 = 0; s2 < 8; ++s2) tot += __popcll(msk[tid][s2]);
        int totp = (tot + 7) & ~7;                 // pad to multiple of 8
        unsigned short* row = actg + ((size_t)tid * NN + n) * 512;
        for (int i = tot; i < totp; ++i) row[i] = 512;   // pad -> zero row
        cntg[tid * NN + n] = totp;
    }
}

__device__ __forceinline__ int bn_lif4(const float* acc, float sc, float of, float vth) {
    float v = 0.0f;
    int bits = 0;
#pragma unroll
    for (int t = 0; t < TT; ++t) {
        float y = acc[t] * sc + of;
        v = v + (y - v) * 0.5f;
        if (v >= vth) { bits |= (1 << t); v = 0.0f; }
    }
    return bits;
}

__global__ __launch_bounds__(256) void ka_qkv(
    float* __restrict__ ws,
    const float* __restrict__ qg, const float* __restrict__ qb,
    const float* __restrict__ qm, const float* __restrict__ qv,
    const float* __restrict__ kg, const float* __restrict__ kb,
    const float* __restrict__ km, const float* __restrict__ kvv,
    const float* __restrict__ vg, const float* __restrict__ vb,
    const float* __restrict__ vm, const float* __restrict__ vvv)
{
    const int bx   = blockIdx.x;
    const int n    = bx >> 1;         // adjacent blocks share n -> L2 locality
    const int s    = bx & 1;
    const int tid  = threadIdx.x;
    const int lane = tid & 63;
    const int wave = tid >> 6;
    const int o    = s * 256 + tid;   // this thread's output channel

    const float* Wqt = ws + WQT_OFF;
    const float* Wkt = ws + WKT_OFF;
    const float* Wvt = ws + WVT_OFF;
    const unsigned short* actg = (const unsigned short*)(ws + ACT_OFF);
    const int* cntg = (const int*)(ws + CNT_OFF);

    float aq[TT] = {0,0,0,0}, ak[TT] = {0,0,0,0}, av[TT] = {0,0,0,0};
#pragma unroll
    for (int t = 0; t < TT; ++t) {
        const int ctp = cntg[t * NN + n];                     // uniform
        const unsigned short* lp = actg + ((size_t)t * NN + n) * 512;
        for (int i = 0; i < ctp; i += 8) {
            const uint4 cc = *(const uint4*)(lp + i);         // 8 entries, uniform
            int cs[8];
            cs[0] = cc.x & 0xffff; cs[1] = cc.x >> 16;
            cs[2] = cc.y & 0xffff; cs[3] = cc.y >> 16;
            cs[4] = cc.z & 0xffff; cs[5] = cc.z >> 16;
            cs[6] = cc.w & 0xffff; cs[7] = cc.w >> 16;
#pragma unroll
            for (int j = 0; j < 8; ++j) {
                const int c = __builtin_amdgcn_readfirstlane(cs[j]);
                const size_t rb = (size_t)c * 512;
                aq[t] += Wqt[rb + o];
                ak[t] += Wkt[rb + o];
                av[t] += Wvt[rb + o];
            }
        }
    }

    // BN + LIF (v_th = 1) for this thread's channel
    int sqb, skb, svb;
    {
        float sc = qg[o] / sqrtf(qv[o] + BEPS);
        sqb = bn_lif4(aq, sc, qb[o] - qm[o] * sc, 1.0f);
        sc = kg[o] / sqrtf(kvv[o] + BEPS);
        skb = bn_lif4(ak, sc, kb[o] - km[o] * sc, 1.0f);
        sc = vg[o] / sqrtf(vvv[o] + BEPS);
        svb = bn_lif4(av, sc, vb[o] - vm[o] * sc, 1.0f);
    }

    unsigned* sqg = (unsigned*)(ws + SQ_OFF);
    float* kvsum = ws + KV_OFF;
#pragma unroll
    for (int t = 0; t < TT; ++t) {
        unsigned long long m = __ballot((sqb >> t) & 1);
        if (lane == 0) {
            sqg[((size_t)t * NN + n) * 16 + s * 8 + wave * 2]     = (unsigned)(m & 0xffffffffULL);
            sqg[((size_t)t * NN + n) * 16 + s * 8 + wave * 2 + 1] = (unsigned)(m >> 32);
        }
        if (((skb >> t) & 1) & ((svb >> t) & 1)) atomicAdd(&kvsum[t * CC + o], 1.0f);
    }
}

__global__ __launch_bounds__(256) void kb_proj(
    const float* __restrict__ ws,
    const float* __restrict__ pbias,
    const float* __restrict__ pg, const float* __restrict__ pb,
    const float* __restrict__ pm, const float* __restrict__ pv,
    float* __restrict__ wso)
{
    const int bx   = blockIdx.x;
    const int n    = bx >> 1;
    const int s    = bx & 1;
    const int tid  = threadIdx.x;
    const int lane = tid & 63;
    const int wave = tid >> 6;
    const int o    = s * 256 + tid;

    __shared__ unsigned long long msk[TT][8];
    __shared__ __align__(16) unsigned short lst[TT][520];
    __shared__ int cntp[TT];

    const float* kvsum = ws + KV_OFF;
    const unsigned* sqg = (const unsigned*)(ws + SQ_OFF);

    // talking-heads LIF (v_th = 0.5) on kvsum; AND with this n's sq bits
    int f0 = 0, f1 = 0;
    {
        float v0 = 0.0f, v1 = 0.0f;
#pragma unroll
        for (int t = 0; t < TT; ++t) {
            float a0 = kvsum[t * CC + tid];
            float a1 = kvsum[t * CC + tid + 256];
            v0 = v0 + (a0 - v0) * 0.5f;
            v1 = v1 + (a1 - v1) * 0.5f;
            const int s0 = (v0 >= 0.5f), s1 = (v1 >= 0.5f);
            if (s0) v0 = 0.0f;
            if (s1) v1 = 0.0f;
            const unsigned w0 = sqg[((size_t)t * NN + n) * 16 + (tid >> 5)];
            const unsigned w1 = sqg[((size_t)t * NN + n) * 16 + 8 + (tid >> 5)];
            if (s0 && ((w0 >> (tid & 31)) & 1)) f0 |= (1 << t);
            if (s1 && ((w1 >> (tid & 31)) & 1)) f1 |= (1 << t);
        }
    }
#pragma unroll
    for (int t = 0; t < TT; ++t) {
        unsigned long long m0 = __ballot((f0 >> t) & 1);
        unsigned long long m1 = __ballot((f1 >> t) & 1);
        if (lane == 0) { msk[t][wave] = m0; msk[t][4 + wave] = m1; }
    }
    __syncthreads();

    const unsigned long long ltm = (1ull << lane) - 1ull;
#pragma unroll
    for (int t = 0; t < TT; ++t) {
        if ((f0 >> t) & 1) {
            int base = 0;
            for (int s2 = 0; s2 < wave; ++s2) base += __popcll(msk[t][s2]);
            base += __popcll(msk[t][wave] & ltm);
            lst[t][base] = (unsigned short)tid;
        }
        if ((f1 >> t) & 1) {
            int base = 0;
            for (int s2 = 0; s2 < 4 + wave; ++s2) base += __popcll(msk[t][s2]);
            base += __popcll(msk[t][4 + wave] & ltm);
            lst[t][base] = (unsigned short)(tid + 256);
        }
    }
    if (tid < TT) {
        int tot = 0;
#pragma unroll
        for (int s2 = 0; s2 < 8; ++s2) tot += __popcll(msk[tid][s2]);
        int totp = (tot + 7) & ~7;
        for (int i = tot; i < totp; ++i) lst[tid][i] = 512;
        cntp[tid] = totp;
    }
    __syncthreads();

    float a[TT] = {0,0,0,0};
    const float* Wpt = ws + WPT_OFF;
#pragma unroll
    for (int t = 0; t < TT; ++t) {
        const int ct = cntp[t];
        for (int i = 0; i < ct; i += 8) {
            const uint4 cc = *(const uint4*)(&lst[t][i]);
            int cs[8];
            cs[0] = cc.x & 0xffff; cs[1] = cc.x >> 16;
            cs[2] = cc.y & 0xffff; cs[3] = cc.y >> 16;
            cs[4] = cc.z & 0xffff; cs[5] = cc.z >> 16;
            cs[6] = cc.w & 0xffff; cs[7] = cc.w >> 16;
#pragma unroll
            for (int j = 0; j < 8; ++j) {
                const int c = __builtin_amdgcn_readfirstlane(cs[j]);
                a[t] += Wpt[(size_t)c * 512 + o];
            }
        }
    }

    // epilogue: (acc + bias)*scale + offset -> coalesced outT[t][n][c]
    {
        const float sc = pg[o] / sqrtf(pv[o] + BEPS);
        const float of = pb[o] - pm[o] * sc;
        const float bi = pbias[o];
        float* outT = wso;
#pragma unroll
        for (int t = 0; t < TT; ++t) {
            outT[((size_t)t * NN + n) * CC + o] = (a[t] + bi) * sc + of;
        }
    }
}

__global__ __launch_bounds__(256) void k2_out(
    const float* __restrict__ x, const float* __restrict__ ws,
    float* __restrict__ out)
{
    // outT[t][n][c] -> out[t][c][n] + x, tiled 64x64, both sides coalesced
    __shared__ float tile[64][65];
    const int b   = blockIdx.x;           // 4t * 8c * 4n = 128
    const int t   = b >> 5;
    const int ct  = (b >> 2) & 7;
    const int nt  = b & 3;
    const int c0  = ct * 64;
    const int n0  = nt * 64;
    const int tid = threadIdx.x;
    const int lr  = tid >> 6;
    const int lc  = tid & 63;
    const float* outT = ws + OT_OFF;
#pragma unroll
    for (int i = 0; i < 16; ++i) {
        int r = i * 4 + lr;               // n-local
        if (n0 + r < NN)
            tile[r][lc] = outT[((size_t)t * NN + (n0 + r)) * CC + c0 + lc];
    }
    __syncthreads();
#pragma unroll
    for (int i = 0; i < 16; ++i) {
        int r = i * 4 + lr;               // c-local
        if (n0 + lc < NN) {
            const size_t gi = ((size_t)t * CC + (c0 + r)) * NN + n0 + lc;
            out[gi] = tile[lc][r] + x[gi];
        }
    }
}

extern "C" void kernel_launch(void* const* d_in, const int* in_sizes, int n_in,
                              void* d_out, int out_size, void* d_ws, size_t ws_size,
                              hipStream_t stream) {
    const float* x     = (const float*)d_in[0];
    const float* qw    = (const float*)d_in[1];
    const float* kw    = (const float*)d_in[2];
    const float* vw    = (const float*)d_in[3];
    const float* pw    = (const float*)d_in[4];
    const float* pbias = (const float*)d_in[5];
    const float* qg = (const float*)d_in[6],  *qb = (const float*)d_in[7];
    const float* qm = (const float*)d_in[8],  *qv = (const float*)d_in[9];
    const float* kg = (const float*)d_in[10], *kb = (const float*)d_in[11];
    const float* km = (const float*)d_in[12], *kv = (const float*)d_in[13];
    const float* vg = (const float*)d_in[14], *vb = (const float*)d_in[15];
    const float* vm = (const float*)d_in[16], *vv = (const float*)d_in[17];
    const float* pg = (const float*)d_in[18], *pb = (const float*)d_in[19];
    const float* pm = (const float*)d_in[20], *pv = (const float*)d_in[21];
    float* ws  = (float*)d_ws;
    float* out = (float*)d_out;

    hipLaunchKernelGGL(k0_prep, dim3(256 + NN), dim3(256), 0, stream,
                       qw, kw, vw, pw, x, ws);
    hipLaunchKernelGGL(ka_qkv, dim3(2 * NN), dim3(256), 0, stream, ws,
                       qg, qb, qm, qv, kg, kb, km, kv, vg, vb, vm, vv);
    hipLaunchKernelGGL(kb_proj, dim3(2 * NN), dim3(256), 0, stream, ws,
                       pbias, pg, pb, pm, pv, ws + OT_OFF);
    hipLaunchKernelGGL(k2_out, dim3(128), dim3(256), 0, stream, x, ws, out);
}

// Round 3
// 123.919 us; speedup vs baseline: 1.0303x; 1.0303x over previous
//
#include <hip/hip_runtime.h>

// MS_SSA_Conv: spiking self-attention, T=4, C=512, N=196 (14x14), fp32.
// All matmul inputs are spikes {0,1} at low density -> sparse masked
// column-sums of W^T instead of dense GEMM.
//
// v3: v2 structure (verified bit-exact) + latency trims. Evidence from v1<->v2
// A/B says dur_us is dominated by harness-fixed overhead (268MB ws re-poison
// fill = 42us + dispatch overhead); kernel sum is ~15-25us. v3 shaves that:
//  k0: 256 blocks total — every block does one 64x64 transpose tile; blocks
//      0..195 ALSO run shortcut-LIF for n=b and build deterministic
//      ascending-c active lists (padded to x8 with c=512 -> zeroed pad row).
//  ka: grid 392 (n, ch-half): list-group uint4 loads software-pipelined
//      (prefetch next group + first group of each t-list upfront), BN params
//      hoisted above gather. 24 independent coalesced loads per group.
//  kb: talking-heads LIF + sq AND, LDS compact, ILP-8 proj gather, epilogue
//      params hoisted, coalesced outT[t][n][c].
//  k2: tiled transpose outT -> out[t][c][n] + identity x.

#define TT 4
#define CC 512
#define NN 196
#define BEPS 1e-5f

// ws layout in floats. Weight mats have 513 rows (row 512 zeroed = pad row).
#define WQT_OFF 0
#define WKT_OFF (513 * 512)
#define WVT_OFF (2 * 513 * 512)
#define WPT_OFF (3 * 513 * 512)
#define KV_OFF  (4 * 513 * 512)          // T*C = 2048 floats
#define SQ_OFF  (KV_OFF + 2048)          // T*N*16 u32 words = 12544
#define ACT_OFF (SQ_OFF + 12544)         // T*N*512 ushorts = 200704 floats
#define CNT_OFF (ACT_OFF + 200704)       // T*N ints = 784
#define OT_OFF  (CNT_OFF + 784)          // T*N*C floats = 401408
// total ~1.67M floats = 6.7 MB of ws

__global__ __launch_bounds__(256) void k0_prep(
    const float* __restrict__ qw, const float* __restrict__ kw,
    const float* __restrict__ vw, const float* __restrict__ pw,
    const float* __restrict__ x, float* __restrict__ ws)
{
    const int b   = blockIdx.x;     // 256 blocks
    const int tid = threadIdx.x;

    // ---- weight transpose: 4 matrices x 64 tiles of 64x64 (all blocks) ----
    {
        __shared__ float tile[64][65];
        const int mat = b >> 6;
        const int t6  = b & 63;
        const int to  = (t6 >> 3) * 64;
        const int tc  = (t6 & 7) * 64;
        const float* W = (mat == 0) ? qw : (mat == 1) ? kw : (mat == 2) ? vw : pw;
        float* Wt = ws + (size_t)mat * (513 * 512);
        const int lr = tid >> 6;
        const int lc = tid & 63;
#pragma unroll
        for (int i = 0; i < 16; ++i) {
            int r = i * 4 + lr;
            tile[r][lc] = W[(size_t)(to + r) * 512 + (tc + lc)];
        }
        __syncthreads();
#pragma unroll
        for (int i = 0; i < 16; ++i) {
            int r = i * 4 + lr;
            Wt[(size_t)(tc + r) * 512 + (to + lc)] = tile[lc][r];
        }
        if (t6 == 0) {  // zero the pad row c=512
            for (int i = tid; i < 512; i += 256) Wt[(size_t)512 * 512 + i] = 0.0f;
        }
        if (b == 0) {
            for (int i = tid; i < TT * CC; i += 256) ws[KV_OFF + i] = 0.0f;
        }
        __syncthreads();
    }

    if (b >= NN) return;

    // ---- shortcut LIF + deterministic active-list build for n=b ----
    const int n    = b;
    const int lane = tid & 63;
    const int wave = tid >> 6;
    __shared__ unsigned long long msk[TT][8];

    int xf0 = 0, xf1 = 0;
    {
        float v0 = 0.0f, v1 = 0.0f;
#pragma unroll
        for (int t = 0; t < TT; ++t) {
            float a0 = x[(size_t)(t * CC + tid) * NN + n];
            float a1 = x[(size_t)(t * CC + tid + 256) * NN + n];
            v0 = v0 + (a0 - v0) * 0.5f;
            v1 = v1 + (a1 - v1) * 0.5f;
            if (v0 >= 1.0f) { xf0 |= (1 << t); v0 = 0.0f; }
            if (v1 >= 1.0f) { xf1 |= (1 << t); v1 = 0.0f; }
        }
    }
#pragma unroll
    for (int t = 0; t < TT; ++t) {
        unsigned long long m0 = __ballot((xf0 >> t) & 1);
        unsigned long long m1 = __ballot((xf1 >> t) & 1);
        if (lane == 0) { msk[t][wave] = m0; msk[t][4 + wave] = m1; }
    }
    __syncthreads();

    unsigned short* actg = (unsigned short*)(ws + ACT_OFF);
    int* cntg = (int*)(ws + CNT_OFF);
    const unsigned long long ltm = (1ull << lane) - 1ull;
#pragma unroll
    for (int t = 0; t < TT; ++t) {
        unsigned short* row = actg + ((size_t)t * NN + n) * 512;
        if ((xf0 >> t) & 1) {
            int base = 0;
            for (int s2 = 0; s2 < wave; ++s2) base += __popcll(msk[t][s2]);
            base += __popcll(msk[t][wave] & ltm);
            row[base] = (unsigned short)tid;
        }
        if ((xf1 >> t) & 1) {
            int base = 0;
            for (int s2 = 0; s2 < 4 + wave; ++s2) base += __popcll(msk[t][s2]);
            base += __popcll(msk[t][4 + wave] & ltm);
            row[base] = (unsigned short)(tid + 256);
        }
    }
    if (tid < TT) {
        int tot = 0;
#pragma unroll
        for (int s2 = 0; s2 < 8; ++s2) tot += __popcll(msk[tid][s2]);
        int totp = (tot + 7) & ~7;                 // pad to multiple of 8
        unsigned short* row = actg + ((size_t)tid * NN + n) * 512;
        for (int i = tot; i < totp; ++i) row[i] = 512;   // pad -> zero row
        cntg[tid * NN + n] = totp;
    }
}

__device__ __forceinline__ int bn_lif4(const float* acc, float sc, float of, float vth) {
    float v = 0.0f;
    int bits = 0;
#pragma unroll
    for (int t = 0; t < TT; ++t) {
        float y = acc[t] * sc + of;
        v = v + (y - v) * 0.5f;
        if (v >= vth) { bits |= (1 << t); v = 0.0f; }
    }
    return bits;
}

__global__ __launch_bounds__(256) void ka_qkv(
    float* __restrict__ ws,
    const float* __restrict__ qg, const float* __restrict__ qb,
    const float* __restrict__ qm, const float* __restrict__ qv,
    const float* __restrict__ kg, const float* __restrict__ kb,
    const float* __restrict__ km, const float* __restrict__ kvv,
    const float* __restrict__ vg, const float* __restrict__ vb,
    const float* __restrict__ vm, const float* __restrict__ vvv)
{
    const int bx   = blockIdx.x;
    const int n    = bx >> 1;         // adjacent blocks share n -> L2 locality
    const int s    = bx & 1;
    const int tid  = threadIdx.x;
    const int lane = tid & 63;
    const int wave = tid >> 6;
    const int o    = s * 256 + tid;   // this thread's output channel

    // hoist BN params: 12 independent loads, latency hides under gather
    const float qg_ = qg[o], qb_ = qb[o], qm_ = qm[o], qv_ = qv[o];
    const float kg_ = kg[o], kb_ = kb[o], km_ = km[o], kv_ = kvv[o];
    const float vg_ = vg[o], vb_ = vb[o], vm_ = vm[o], vv_ = vvv[o];

    const float* Wqt = ws + WQT_OFF;
    const float* Wkt = ws + WKT_OFF;
    const float* Wvt = ws + WVT_OFF;
    const unsigned short* actg = (const unsigned short*)(ws + ACT_OFF);
    const int* cntg = (const int*)(ws + CNT_OFF);

    // hoist all 4 counts + first list group of each t (static t indexing)
    const int ct0 = cntg[0 * NN + n];
    const int ct1 = cntg[1 * NN + n];
    const int ct2 = cntg[2 * NN + n];
    const int ct3 = cntg[3 * NN + n];
    const unsigned short* lp0 = actg + ((size_t)0 * NN + n) * 512;
    const unsigned short* lp1 = actg + ((size_t)1 * NN + n) * 512;
    const unsigned short* lp2 = actg + ((size_t)2 * NN + n) * 512;
    const unsigned short* lp3 = actg + ((size_t)3 * NN + n) * 512;
    uint4 cur0, cur1, cur2, cur3;
    if (ct0 > 0) cur0 = *(const uint4*)lp0;
    if (ct1 > 0) cur1 = *(const uint4*)lp1;
    if (ct2 > 0) cur2 = *(const uint4*)lp2;
    if (ct3 > 0) cur3 = *(const uint4*)lp3;

    float aq[TT] = {0,0,0,0}, ak[TT] = {0,0,0,0}, av[TT] = {0,0,0,0};

#define KA_GATHER(T, CT, LP, CUR)                                            \
    for (int i = 0; i < (CT); i += 8) {                                      \
        uint4 nxt = CUR;                                                     \
        if (i + 8 < (CT)) nxt = *(const uint4*)((LP) + i + 8);               \
        int cs[8];                                                           \
        cs[0] = CUR.x & 0xffff; cs[1] = CUR.x >> 16;                         \
        cs[2] = CUR.y & 0xffff; cs[3] = CUR.y >> 16;                         \
        cs[4] = CUR.z & 0xffff; cs[5] = CUR.z >> 16;                         \
        cs[6] = CUR.w & 0xffff; cs[7] = CUR.w >> 16;                         \
        _Pragma("unroll")                                                    \
        for (int j = 0; j < 8; ++j) {                                        \
            const int c = __builtin_amdgcn_readfirstlane(cs[j]);             \
            const size_t rb = (size_t)c * 512;                               \
            aq[T] += Wqt[rb + o];                                            \
            ak[T] += Wkt[rb + o];                                            \
            av[T] += Wvt[rb + o];                                            \
        }                                                                    \
        CUR = nxt;                                                           \
    }

    KA_GATHER(0, ct0, lp0, cur0)
    KA_GATHER(1, ct1, lp1, cur1)
    KA_GATHER(2, ct2, lp2, cur2)
    KA_GATHER(3, ct3, lp3, cur3)
#undef KA_GATHER

    // BN + LIF (v_th = 1) for this thread's channel
    int sqb, skb, svb;
    {
        float sc = qg_ / sqrtf(qv_ + BEPS);
        sqb = bn_lif4(aq, sc, qb_ - qm_ * sc, 1.0f);
        sc = kg_ / sqrtf(kv_ + BEPS);
        skb = bn_lif4(ak, sc, kb_ - km_ * sc, 1.0f);
        sc = vg_ / sqrtf(vv_ + BEPS);
        svb = bn_lif4(av, sc, vb_ - vm_ * sc, 1.0f);
    }

    unsigned* sqg = (unsigned*)(ws + SQ_OFF);
    float* kvsum = ws + KV_OFF;
#pragma unroll
    for (int t = 0; t < TT; ++t) {
        unsigned long long m = __ballot((sqb >> t) & 1);
        if (lane == 0) {
            sqg[((size_t)t * NN + n) * 16 + s * 8 + wave * 2]     = (unsigned)(m & 0xffffffffULL);
            sqg[((size_t)t * NN + n) * 16 + s * 8 + wave * 2 + 1] = (unsigned)(m >> 32);
        }
        if (((skb >> t) & 1) & ((svb >> t) & 1)) atomicAdd(&kvsum[t * CC + o], 1.0f);
    }
}

__global__ __launch_bounds__(256) void kb_proj(
    const float* __restrict__ ws,
    const float* __restrict__ pbias,
    const float* __restrict__ pg, const float* __restrict__ pb,
    const float* __restrict__ pm, const float* __restrict__ pv,
    float* __restrict__ wso)
{
    const int bx   = blockIdx.x;
    const int n    = bx >> 1;
    const int s    = bx & 1;
    const int tid  = threadIdx.x;
    const int lane = tid & 63;
    const int wave = tid >> 6;
    const int o    = s * 256 + tid;

    // hoist epilogue params above gather
    const float pg_ = pg[o], pb_ = pb[o], pm_ = pm[o], pv_ = pv[o], bi = pbias[o];

    __shared__ unsigned long long msk[TT][8];
    __shared__ __align__(16) unsigned short lst[TT][520];
    __shared__ int cntp[TT];

    const float* kvsum = ws + KV_OFF;
    const unsigned* sqg = (const unsigned*)(ws + SQ_OFF);

    // talking-heads LIF (v_th = 0.5) on kvsum; AND with this n's sq bits
    int f0 = 0, f1 = 0;
    {
        float v0 = 0.0f, v1 = 0.0f;
#pragma unroll
        for (int t = 0; t < TT; ++t) {
            float a0 = kvsum[t * CC + tid];
            float a1 = kvsum[t * CC + tid + 256];
            v0 = v0 + (a0 - v0) * 0.5f;
            v1 = v1 + (a1 - v1) * 0.5f;
            const int s0 = (v0 >= 0.5f), s1 = (v1 >= 0.5f);
            if (s0) v0 = 0.0f;
            if (s1) v1 = 0.0f;
            const unsigned w0 = sqg[((size_t)t * NN + n) * 16 + (tid >> 5)];
            const unsigned w1 = sqg[((size_t)t * NN + n) * 16 + 8 + (tid >> 5)];
            if (s0 && ((w0 >> (tid & 31)) & 1)) f0 |= (1 << t);
            if (s1 && ((w1 >> (tid & 31)) & 1)) f1 |= (1 << t);
        }
    }
#pragma unroll
    for (int t = 0; t < TT; ++t) {
        unsigned long long m0 = __ballot((f0 >> t) & 1);
        unsigned long long m1 = __ballot((f1 >> t) & 1);
        if (lane == 0) { msk[t][wave] = m0; msk[t][4 + wave] = m1; }
    }
    __syncthreads();

    const unsigned long long ltm = (1ull << lane) - 1ull;
#pragma unroll
    for (int t = 0; t < TT; ++t) {
        if ((f0 >> t) & 1) {
            int base = 0;
            for (int s2 = 0; s2 < wave; ++s2) base += __popcll(msk[t][s2]);
            base += __popcll(msk[t][wave] & ltm);
            lst[t][base] = (unsigned short)tid;
        }
        if ((f1 >> t) & 1) {
            int base = 0;
            for (int s2 = 0; s2 < 4 + wave; ++s2) base += __popcll(msk[t][s2]);
            base += __popcll(msk[t][4 + wave] & ltm);
            lst[t][base] = (unsigned short)(tid + 256);
        }
    }
    if (tid < TT) {
        int tot = 0;
#pragma unroll
        for (int s2 = 0; s2 < 8; ++s2) tot += __popcll(msk[tid][s2]);
        int totp = (tot + 7) & ~7;
        for (int i = tot; i < totp; ++i) lst[tid][i] = 512;
        cntp[tid] = totp;
    }
    __syncthreads();

    float a[TT] = {0,0,0,0};
    const float* Wpt = ws + WPT_OFF;
#pragma unroll
    for (int t = 0; t < TT; ++t) {
        const int ct = cntp[t];
        for (int i = 0; i < ct; i += 8) {
            const uint4 cc = *(const uint4*)(&lst[t][i]);
            int cs[8];
            cs[0] = cc.x & 0xffff; cs[1] = cc.x >> 16;
            cs[2] = cc.y & 0xffff; cs[3] = cc.y >> 16;
            cs[4] = cc.z & 0xffff; cs[5] = cc.z >> 16;
            cs[6] = cc.w & 0xffff; cs[7] = cc.w >> 16;
#pragma unroll
            for (int j = 0; j < 8; ++j) {
                const int c = __builtin_amdgcn_readfirstlane(cs[j]);
                a[t] += Wpt[(size_t)c * 512 + o];
            }
        }
    }

    // epilogue: (acc + bias)*scale + offset -> coalesced outT[t][n][c]
    {
        const float sc = pg_ / sqrtf(pv_ + BEPS);
        const float of = pb_ - pm_ * sc;
        float* outT = wso;
#pragma unroll
        for (int t = 0; t < TT; ++t) {
            outT[((size_t)t * NN + n) * CC + o] = (a[t] + bi) * sc + of;
        }
    }
}

__global__ __launch_bounds__(256) void k2_out(
    const float* __restrict__ x, const float* __restrict__ ws,
    float* __restrict__ out)
{
    // outT[t][n][c] -> out[t][c][n] + x, tiled 64x64, both sides coalesced
    __shared__ float tile[64][65];
    const int b   = blockIdx.x;           // 4t * 8c * 4n = 128
    const int t   = b >> 5;
    const int ct  = (b >> 2) & 7;
    const int nt  = b & 3;
    const int c0  = ct * 64;
    const int n0  = nt * 64;
    const int tid = threadIdx.x;
    const int lr  = tid >> 6;
    const int lc  = tid & 63;
    const float* outT = ws + OT_OFF;
#pragma unroll
    for (int i = 0; i < 16; ++i) {
        int r = i * 4 + lr;               // n-local
        if (n0 + r < NN)
            tile[r][lc] = outT[((size_t)t * NN + (n0 + r)) * CC + c0 + lc];
    }
    __syncthreads();
#pragma unroll
    for (int i = 0; i < 16; ++i) {
        int r = i * 4 + lr;               // c-local
        if (n0 + lc < NN) {
            const size_t gi = ((size_t)t * CC + (c0 + r)) * NN + n0 + lc;
            out[gi] = tile[lc][r] + x[gi];
        }
    }
}

extern "C" void kernel_launch(void* const* d_in, const int* in_sizes, int n_in,
                              void* d_out, int out_size, void* d_ws, size_t ws_size,
                              hipStream_t stream) {
    const float* x     = (const float*)d_in[0];
    const float* qw    = (const float*)d_in[1];
    const float* kw    = (const float*)d_in[2];
    const float* vw    = (const float*)d_in[3];
    const float* pw    = (const float*)d_in[4];
    const float* pbias = (const float*)d_in[5];
    const float* qg = (const float*)d_in[6],  *qb = (const float*)d_in[7];
    const float* qm = (const float*)d_in[8],  *qv = (const float*)d_in[9];
    const float* kg = (const float*)d_in[10], *kb = (const float*)d_in[11];
    const float* km = (const float*)d_in[12], *kv = (const float*)d_in[13];
    const float* vg = (const float*)d_in[14], *vb = (const float*)d_in[15];
    const float* vm = (const float*)d_in[16], *vv = (const float*)d_in[17];
    const float* pg = (const float*)d_in[18], *pb = (const float*)d_in[19];
    const float* pm = (const float*)d_in[20], *pv = (const float*)d_in[21];
    float* ws  = (float*)d_ws;
    float* out = (float*)d_out;

    hipLaunchKernelGGL(k0_prep, dim3(256), dim3(256), 0, stream,
                       qw, kw, vw, pw, x, ws);
    hipLaunchKernelGGL(ka_qkv, dim3(2 * NN), dim3(256), 0, stream, ws,
                       qg, qb, qm, qv, kg, kb, km, kv, vg, vb, vm, vv);
    hipLaunchKernelGGL(kb_proj, dim3(2 * NN), dim3(256), 0, stream, ws,
                       pbias, pg, pb, pm, pv, ws + OT_OFF);
    hipLaunchKernelGGL(k2_out, dim3(128), dim3(256), 0, stream, x, ws, out);
}